// Round 2
// baseline (97.564 us; speedup 1.0000x reference)
//
#include <hip/hip_runtime.h>
#include <math.h>

#define MAXN 8400
#define TOPK 10

// Grid-stride float4 zero-fill. out bytes must be 16B-divisible (it is:
// B*N*85*4 = 182,784,000 = 16 * 11,424,000).
__global__ __launch_bounds__(256) void zero_fill_kernel(float4* __restrict__ out, size_t n4)
{
    const size_t stride = (size_t)gridDim.x * blockDim.x;
    const float4 z = make_float4(0.f, 0.f, 0.f, 0.f);
    for (size_t i = (size_t)blockIdx.x * blockDim.x + threadIdx.x; i < n4; i += stride)
        out[i] = z;
}

__global__ __launch_bounds__(256) void taa_kernel(
    const float* __restrict__ scores,   // B,N,C
    const float* __restrict__ boxes,    // B,N,4
    const float* __restrict__ anchors,  // N,2
    const int*   __restrict__ labels,   // B
    const float* __restrict__ gts,      // B,1,4
    float* __restrict__ tb,             // B,N,4
    float* __restrict__ ts,             // B,N,C
    float* __restrict__ fg,             // B,N
    int N, int C)
{
    const int b   = blockIdx.x;
    const int tid = threadIdx.x;

    const float g0 = gts[b*4+0], g1 = gts[b*4+1], g2 = gts[b*4+2], g3 = gts[b*4+3];
    const bool  gt_valid = (g2 > g0) && (g3 > g1);
    const int   cls = labels[b];
    const float gcx = (g0 + g2) * 0.5f, gcy = (g1 + g3) * 0.5f;
    const float area_g = (g2 - g0) * (g3 - g1);

    __shared__ float s_metric[MAXN];
    __shared__ float s_iou[MAXN];
    __shared__ float r_val[256];
    __shared__ int   r_idx[256];
    __shared__ int   s_any;

    if (tid == 0) s_any = 0;
    __syncthreads();

    // Pass 1: per-anchor metric (masked by is_in), iou; track local argmin d2.
    float best_d2 = INFINITY;
    int   best_di = 0x7fffffff;
    int   any_local = 0;

    for (int i = tid; i < N; i += blockDim.x) {
        const float ax = anchors[2*i + 0];
        const float ay = anchors[2*i + 1];
        const bool is_in = (ax >= g0) && (ax <= g2) && (ay >= g1) && (ay <= g3);
        any_local |= (int)is_in;

        const float dx = ax - gcx, dy = ay - gcy;
        const float d2 = dx*dx + dy*dy;
        if (d2 < best_d2) { best_d2 = d2; best_di = i; }  // strided ascending -> first min kept

        const size_t bi4 = ((size_t)b * N + i) * 4;
        const float bx0 = boxes[bi4+0], by0 = boxes[bi4+1];
        const float bx1 = boxes[bi4+2], by1 = boxes[bi4+3];
        const float ix1 = fmaxf(bx0, g0), iy1 = fmaxf(by0, g1);
        const float ix2 = fminf(bx1, g2), iy2 = fminf(by1, g3);
        const float inter = fmaxf(ix2 - ix1, 0.0f) * fmaxf(iy2 - iy1, 0.0f);
        const float area_p = (bx1 - bx0) * (by1 - by0);
        float iou = inter / (area_p + area_g - inter);
        iou = fmaxf(iou, 1e-9f);
        s_iou[i] = iou;

        const float sc = scores[((size_t)b * N + i) * C + cls];
        const float cs = 1.0f / (1.0f + expf(-sc));
        const float i2 = iou * iou;
        const float m  = sqrtf(cs) * (i2 * i2 * i2);

        s_metric[i] = is_in ? m : -1.0f;
    }
    if (any_local) atomicOr(&s_any, 1);
    __syncthreads();

    // Fallback: no anchor inside gt box -> enable only the argmin-d2 anchor.
    if (!s_any) {
        r_val[tid] = best_d2;
        r_idx[tid] = best_di;
        __syncthreads();
        for (int s = 128; s > 0; s >>= 1) {
            if (tid < s) {
                const float v2 = r_val[tid+s]; const int i2x = r_idx[tid+s];
                if (v2 < r_val[tid] || (v2 == r_val[tid] && i2x < r_idx[tid])) {
                    r_val[tid] = v2; r_idx[tid] = i2x;
                }
            }
            __syncthreads();
        }
        if (tid == 0) {
            const int fi = r_idx[0];
            const float sc = scores[((size_t)b * N + fi) * C + cls];
            const float cs = 1.0f / (1.0f + expf(-sc));
            const float iou = s_iou[fi];
            const float i2 = iou * iou;
            s_metric[fi] = sqrtf(cs) * (i2 * i2 * i2);
        }
        __syncthreads();
    }

    // Top-10: sequential block argmax with lowest-index tie-break (top_k stability).
    for (int k = 0; k < TOPK; ++k) {
        float bv = -INFINITY;
        int   bix = 0x7fffffff;
        for (int i = tid; i < N; i += blockDim.x) {
            const float v = s_metric[i];
            if (v > bv) { bv = v; bix = i; }   // ascending stride -> first occurrence kept
        }
        r_val[tid] = bv;
        r_idx[tid] = bix;
        __syncthreads();
        for (int s = 128; s > 0; s >>= 1) {
            if (tid < s) {
                const float v2 = r_val[tid+s]; const int i2x = r_idx[tid+s];
                if (v2 > r_val[tid] || (v2 == r_val[tid] && i2x < r_idx[tid])) {
                    r_val[tid] = v2; r_idx[tid] = i2x;
                }
            }
            __syncthreads();
        }
        const int   wi = r_idx[0];
        const float wv = r_val[0];
        if (tid == 0) {
            s_metric[wi] = -INFINITY;  // remove from further rounds
            const bool sel = (wv >= 0.0f) && gt_valid;
            if (sel) {
                fg[(size_t)b * N + wi] = 1.0f;
                float* tbp = tb + ((size_t)b * N + wi) * 4;
                tbp[0] = g0; tbp[1] = g1; tbp[2] = g2; tbp[3] = g3;
                ts[((size_t)b * N + wi) * C + cls] = s_iou[wi];
            }
        }
        __syncthreads();
    }
}

extern "C" void kernel_launch(void* const* d_in, const int* in_sizes, int n_in,
                              void* d_out, int out_size, void* d_ws, size_t ws_size,
                              hipStream_t stream) {
    const float* scores  = (const float*)d_in[0];
    const float* boxes   = (const float*)d_in[1];
    const float* anchors = (const float*)d_in[2];
    const int*   labels  = (const int*)d_in[3];
    const float* gts     = (const float*)d_in[4];

    const int B = in_sizes[3];
    const int N = in_sizes[2] / 2;
    const int C = in_sizes[0] / (B * N);

    float* tb = (float*)d_out;
    float* ts = tb + (size_t)B * N * 4;
    float* fg = ts + (size_t)B * N * C;

    // Outputs are almost entirely zeros; zero-fill (custom float4 kernel — the
    // runtime's fillBufferAligned ran at only ~1.8 TB/s) then scatter winners.
    const size_t n4 = ((size_t)out_size * sizeof(float)) / sizeof(float4);
    zero_fill_kernel<<<2048, 256, 0, stream>>>((float4*)d_out, n4);

    taa_kernel<<<B, 256, 0, stream>>>(scores, boxes, anchors, labels, gts,
                                      tb, ts, fg, N, C);
}

// Round 3
// 73.283 us; speedup vs baseline: 1.3313x; 1.3313x over previous
//
#include <hip/hip_runtime.h>
#include <math.h>

#define TOPK 10
#define NTHREADS 1024
#define PER_THREAD 9   // ceil(8400 / 1024)

// ---------- helpers ----------

// Order-preserving f32 -> u32 (monotone: a<b  =>  enc(a)<enc(b)).
__device__ __forceinline__ unsigned int f32_ordkey(float f) {
    unsigned int u = __float_as_uint(f);
    return (u & 0x80000000u) ? ~u : (u | 0x80000000u);
}

__device__ __forceinline__ unsigned long long wave_max_u64(unsigned long long k) {
    #pragma unroll
    for (int off = 32; off > 0; off >>= 1) {
        unsigned long long o = __shfl_xor(k, off, 64);
        k = (o > k) ? o : k;
    }
    return k;
}

__device__ __forceinline__ unsigned long long wave_min_u64(unsigned long long k) {
    #pragma unroll
    for (int off = 32; off > 0; off >>= 1) {
        unsigned long long o = __shfl_xor(k, off, 64);
        k = (o < k) ? o : k;
    }
    return k;
}

// ---------- kernels ----------

// Grid-stride float4 zero-fill (183 MB; out bytes are 16B-divisible).
__global__ __launch_bounds__(256) void zero_fill_kernel(float4* __restrict__ out, size_t n4)
{
    const size_t stride = (size_t)gridDim.x * blockDim.x;
    const float4 z = make_float4(0.f, 0.f, 0.f, 0.f);
    for (size_t i = (size_t)blockIdx.x * blockDim.x + threadIdx.x; i < n4; i += stride)
        out[i] = z;
}

__global__ __launch_bounds__(NTHREADS) void taa_kernel(
    const float* __restrict__ scores,   // B,N,C
    const float* __restrict__ boxes,    // B,N,4
    const float* __restrict__ anchors,  // N,2
    const int*   __restrict__ labels,   // B
    const float* __restrict__ gts,      // B,1,4
    float* __restrict__ tb,             // B,N,4
    float* __restrict__ ts,             // B,N,C
    float* __restrict__ fg,             // B,N
    int N, int C)
{
    const int b    = blockIdx.x;
    const int tid  = threadIdx.x;
    const int lane = tid & 63;
    const int wave = tid >> 6;          // 0..15

    const float g0 = gts[b*4+0], g1 = gts[b*4+1], g2 = gts[b*4+2], g3 = gts[b*4+3];
    const bool  gt_valid = (g2 > g0) && (g3 > g1);
    const int   cls = labels[b];
    const float gcx = (g0 + g2) * 0.5f, gcy = (g1 + g3) * 0.5f;
    const float area_g = (g2 - g0) * (g3 - g1);

    __shared__ unsigned long long s_dk[16];
    __shared__ int                s_anyw[16];
    __shared__ unsigned long long s_fb;
    __shared__ int                s_anyflag;
    __shared__ unsigned long long s_cand[16 * TOPK];
    __shared__ unsigned long long s_win[TOPK];

    // Pass 1: per-anchor metric into registers; track is_in mask and argmin-d2.
    float        metric[PER_THREAD];
    unsigned int inmask = 0;
    unsigned long long dkey = ~0ull;    // min of (bits(d2)<<32 | idx); d2>=0 so raw bits are monotone

    #pragma unroll
    for (int j = 0; j < PER_THREAD; ++j) {
        const int i = tid + j * NTHREADS;
        if (i < N) {
            const float ax = anchors[2*i + 0];
            const float ay = anchors[2*i + 1];
            const bool  in = (ax >= g0) && (ax <= g2) && (ay >= g1) && (ay <= g3);
            if (in) inmask |= (1u << j);

            const float dx = ax - gcx, dy = ay - gcy;
            const float d2 = dx*dx + dy*dy;
            const unsigned long long dk =
                ((unsigned long long)__float_as_uint(d2) << 32) | (unsigned int)i;
            dkey = dk < dkey ? dk : dkey;   // ties: smaller idx wins automatically (lower bits)

            const float4 bx = ((const float4*)boxes)[(size_t)b * N + i];
            const float ix1 = fmaxf(bx.x, g0), iy1 = fmaxf(bx.y, g1);
            const float ix2 = fminf(bx.z, g2), iy2 = fminf(bx.w, g3);
            const float inter  = fmaxf(ix2 - ix1, 0.0f) * fmaxf(iy2 - iy1, 0.0f);
            const float area_p = (bx.z - bx.x) * (bx.w - bx.y);
            const float iou = fmaxf(inter / (area_p + area_g - inter), 1e-9f);

            const float sc = scores[((size_t)b * N + i) * C + cls];
            const float cs = 1.0f / (1.0f + expf(-sc));
            const float i2 = iou * iou;
            metric[j] = sqrtf(cs) * (i2 * i2 * i2);
        } else {
            metric[j] = -2.0f;          // pad; key forced to 0 below
        }
    }

    // Block reduce: any(is_in) and argmin d2 (first occurrence on ties).
    {
        const unsigned long long wdk = wave_min_u64(dkey);
        const int wany = __any(inmask != 0);
        if (lane == 0) { s_dk[wave] = wdk; s_anyw[wave] = wany; }
    }
    __syncthreads();
    if (wave == 0) {
        unsigned long long v = (lane < 16) ? s_dk[lane] : ~0ull;
        int a = (lane < 16) ? s_anyw[lane] : 0;
        v = wave_min_u64(v);
        a = __any(a);
        if (lane == 0) { s_fb = v; s_anyflag = a; }
    }
    __syncthreads();
    const bool any_in = (s_anyflag != 0);
    const int  fi     = (int)(s_fb & 0xffffffffu);

    // Build sortable keys: (ordkey(masked metric) << 32) | ~idx  — max = best, ties -> lowest idx.
    unsigned long long key[PER_THREAD];
    #pragma unroll
    for (int j = 0; j < PER_THREAD; ++j) {
        const int i = tid + j * NTHREADS;
        if (i < N) {
            const bool valid = any_in ? (((inmask >> j) & 1u) != 0) : (i == fi);
            const float m = valid ? metric[j] : -1.0f;
            key[j] = ((unsigned long long)f32_ordkey(m) << 32) | (unsigned int)(~(unsigned int)i);
        } else {
            key[j] = 0ull;              // below any real key (real min is key(-1.0) > 0)
        }
    }

    // Wave-level top-10 by iterative max + zero-out (keys unique: idx in low bits).
    for (int r = 0; r < TOPK; ++r) {
        unsigned long long lm = key[0];
        #pragma unroll
        for (int j = 1; j < PER_THREAD; ++j) lm = key[j] > lm ? key[j] : lm;
        const unsigned long long w = wave_max_u64(lm);
        #pragma unroll
        for (int j = 0; j < PER_THREAD; ++j) if (key[j] == w) key[j] = 0ull;
        if (lane == 0) s_cand[wave * TOPK + r] = w;
    }
    __syncthreads();

    // Merge 16 waves x 10 candidates -> global top-10 (wave 0).
    if (wave == 0) {
        unsigned long long c0 = s_cand[lane];
        unsigned long long c1 = s_cand[lane + 64];
        unsigned long long c2 = (lane < 32) ? s_cand[lane + 128] : 0ull;
        for (int r = 0; r < TOPK; ++r) {
            unsigned long long lm = c0 > c1 ? c0 : c1;
            lm = c2 > lm ? c2 : lm;
            const unsigned long long w = wave_max_u64(lm);
            if (c0 == w) c0 = 0ull;
            if (c1 == w) c1 = 0ull;
            if (c2 == w) c2 = 0ull;
            if (lane == 0) s_win[r] = w;
        }
    }
    __syncthreads();

    // Scatter winners. sel <=> metric >= 0 <=> top bit of ordkey set.
    if (tid < TOPK) {
        const unsigned long long w = s_win[tid];
        const unsigned int mk = (unsigned int)(w >> 32);
        if (gt_valid && (mk & 0x80000000u)) {
            const int i = (int)(~(unsigned int)(w & 0xffffffffu));
            const float4 bx = ((const float4*)boxes)[(size_t)b * N + i];
            const float ix1 = fmaxf(bx.x, g0), iy1 = fmaxf(bx.y, g1);
            const float ix2 = fminf(bx.z, g2), iy2 = fminf(bx.w, g3);
            const float inter  = fmaxf(ix2 - ix1, 0.0f) * fmaxf(iy2 - iy1, 0.0f);
            const float area_p = (bx.z - bx.x) * (bx.w - bx.y);
            const float iou = fmaxf(inter / (area_p + area_g - inter), 1e-9f);

            fg[(size_t)b * N + i] = 1.0f;
            ((float4*)tb)[(size_t)b * N + i] = make_float4(g0, g1, g2, g3);
            ts[((size_t)b * N + i) * C + cls] = iou;
        }
    }
}

extern "C" void kernel_launch(void* const* d_in, const int* in_sizes, int n_in,
                              void* d_out, int out_size, void* d_ws, size_t ws_size,
                              hipStream_t stream) {
    const float* scores  = (const float*)d_in[0];
    const float* boxes   = (const float*)d_in[1];
    const float* anchors = (const float*)d_in[2];
    const int*   labels  = (const int*)d_in[3];
    const float* gts     = (const float*)d_in[4];

    const int B = in_sizes[3];
    const int N = in_sizes[2] / 2;
    const int C = in_sizes[0] / (B * N);

    float* tb = (float*)d_out;
    float* ts = tb + (size_t)B * N * 4;
    float* fg = ts + (size_t)B * N * C;

    const size_t n4 = ((size_t)out_size * sizeof(float)) / sizeof(float4);
    zero_fill_kernel<<<2048, 256, 0, stream>>>((float4*)d_out, n4);

    taa_kernel<<<B, NTHREADS, 0, stream>>>(scores, boxes, anchors, labels, gts,
                                           tb, ts, fg, N, C);
}

// Round 4
// 59.270 us; speedup vs baseline: 1.6461x; 1.2364x over previous
//
#include <hip/hip_runtime.h>
#include <math.h>

#define TOPK 10
#define G 8              // blocks per batch (stage 1)
#define CHUNK 1050       // N / G
#define S1_THREADS 256
#define S1_PER 5         // ceil(CHUNK / S1_THREADS)

struct FB { unsigned long long dkey; float met; float iou; };  // 16 B

// ---------- helpers ----------

// Order-preserving f32 -> u32 (monotone: a<b  =>  enc(a)<enc(b)).
__device__ __forceinline__ unsigned int f32_ordkey(float f) {
    unsigned int u = __float_as_uint(f);
    return (u & 0x80000000u) ? ~u : (u | 0x80000000u);
}

__device__ __forceinline__ unsigned long long wave_max_u64(unsigned long long k) {
    #pragma unroll
    for (int off = 32; off > 0; off >>= 1) {
        unsigned long long o = __shfl_xor(k, off, 64);
        k = (o > k) ? o : k;
    }
    return k;
}

__device__ __forceinline__ unsigned long long wave_min_u64(unsigned long long k) {
    #pragma unroll
    for (int off = 32; off > 0; off >>= 1) {
        unsigned long long o = __shfl_xor(k, off, 64);
        k = (o < k) ? o : k;
    }
    return k;
}

// ---------- kernels ----------

// Grid-stride float4 zero-fill (183 MB; out bytes are 16B-divisible).
__global__ __launch_bounds__(256) void zero_fill_kernel(float4* __restrict__ out, size_t n4)
{
    const size_t stride = (size_t)gridDim.x * blockDim.x;
    const float4 z = make_float4(0.f, 0.f, 0.f, 0.f);
    for (size_t i = (size_t)blockIdx.x * blockDim.x + threadIdx.x; i < n4; i += stride)
        out[i] = z;
}

// Stage 1: grid = B*G blocks x 256 threads. Block (b,g) covers anchors
// [g*CHUNK, (g+1)*CHUNK). Emits per wave: top-10 keys, any(is_in), min-d2
// record. Wave-level shuffles only — no __syncthreads.
__global__ __launch_bounds__(S1_THREADS) void taa_stage1(
    const float* __restrict__ scores,   // B,N,C
    const float* __restrict__ boxes,    // B,N,4
    const float* __restrict__ anchors,  // N,2
    const int*   __restrict__ labels,   // B
    const float* __restrict__ gts,      // B,1,4
    unsigned long long* __restrict__ cand,  // [B][G*4*TOPK] = [B][320]
    FB*  __restrict__ fbr,                  // [B][G*4]      = [B][32]
    int* __restrict__ anyf,                 // [B][G*4]      = [B][32]
    int N, int C)
{
    const int b    = blockIdx.x / G;
    const int g    = blockIdx.x % G;
    const int tid  = threadIdx.x;
    const int lane = tid & 63;
    const int wave = tid >> 6;          // 0..3
    const int base = g * CHUNK;

    const float g0 = gts[b*4+0], g1 = gts[b*4+1], g2 = gts[b*4+2], g3 = gts[b*4+3];
    const int   cls = labels[b];
    const float gcx = (g0 + g2) * 0.5f, gcy = (g1 + g3) * 0.5f;
    const float area_g = (g2 - g0) * (g3 - g1);

    float met[S1_PER], iou[S1_PER];
    unsigned int inmask = 0;
    unsigned long long dkey = ~0ull;
    int jmin = 0;

    #pragma unroll
    for (int j = 0; j < S1_PER; ++j) {
        const int ii = tid + j * S1_THREADS;
        const int i  = base + ii;
        if (ii < CHUNK) {
            const float2 a = ((const float2*)anchors)[i];
            const bool in = (a.x >= g0) && (a.x <= g2) && (a.y >= g1) && (a.y <= g3);
            if (in) inmask |= (1u << j);

            const float dx = a.x - gcx, dy = a.y - gcy;
            const float d2 = dx*dx + dy*dy;
            const unsigned long long dk =
                ((unsigned long long)__float_as_uint(d2) << 32) | (unsigned int)i;
            if (dk < dkey) { dkey = dk; jmin = j; }

            const float4 bx = ((const float4*)boxes)[(size_t)b * N + i];
            const float ix1 = fmaxf(bx.x, g0), iy1 = fmaxf(bx.y, g1);
            const float ix2 = fminf(bx.z, g2), iy2 = fminf(bx.w, g3);
            const float inter  = fmaxf(ix2 - ix1, 0.0f) * fmaxf(iy2 - iy1, 0.0f);
            const float area_p = (bx.z - bx.x) * (bx.w - bx.y);
            iou[j] = fmaxf(inter / (area_p + area_g - inter), 1e-9f);

            const float sc = scores[((size_t)b * N + i) * C + cls];
            const float cs = 1.0f / (1.0f + expf(-sc));
            const float i2 = iou[j] * iou[j];
            met[j] = sqrtf(cs) * (i2 * i2 * i2);
        } else {
            met[j] = -2.0f; iou[j] = 0.0f;
        }
    }

    // Sortable keys: (ordkey(masked metric) << 32) | ~idx. Max = best; ties -> lowest idx.
    unsigned long long key[S1_PER];
    #pragma unroll
    for (int j = 0; j < S1_PER; ++j) {
        const int ii = tid + j * S1_THREADS;
        const int i  = base + ii;
        if (ii < CHUNK) {
            const float m = ((inmask >> j) & 1u) ? met[j] : -1.0f;
            key[j] = ((unsigned long long)f32_ordkey(m) << 32) | (unsigned int)(~(unsigned int)i);
        } else {
            key[j] = 0ull;   // below any real key (key(-1.0) > 0)
        }
    }

    // Wave top-10 by iterative max + zero-out (keys unique).
    unsigned long long* wc = cand + ((size_t)b * (G*4*TOPK)) + (g*4 + wave) * TOPK;
    for (int r = 0; r < TOPK; ++r) {
        unsigned long long lm = key[0];
        #pragma unroll
        for (int j = 1; j < S1_PER; ++j) lm = key[j] > lm ? key[j] : lm;
        const unsigned long long w = wave_max_u64(lm);
        #pragma unroll
        for (int j = 0; j < S1_PER; ++j) if (key[j] == w) key[j] = 0ull;
        if (lane == 0) wc[r] = w;
    }

    // Wave any(is_in) + min-d2 record (the unique lane holding the min writes).
    const int wany = __any(inmask != 0);
    const unsigned long long wdk = wave_min_u64(dkey);
    if (lane == 0) anyf[b * (G*4) + g*4 + wave] = wany;
    if (dkey == wdk) {
        FB r; r.dkey = wdk; r.met = met[jmin]; r.iou = iou[jmin];
        fbr[b * (G*4) + g*4 + wave] = r;
    }
}

// Stage 2: grid = B blocks x 64 threads. Merge 320 candidates -> top-10 -> scatter.
__global__ __launch_bounds__(64) void taa_stage2(
    const float* __restrict__ boxes,    // B,N,4
    const int*   __restrict__ labels,   // B
    const float* __restrict__ gts,      // B,1,4
    const unsigned long long* __restrict__ cand,
    const FB*  __restrict__ fbr,
    const int* __restrict__ anyf,
    float* __restrict__ tb, float* __restrict__ ts, float* __restrict__ fg,
    int N, int C)
{
    const int b    = blockIdx.x;
    const int lane = threadIdx.x;

    const float g0 = gts[b*4+0], g1 = gts[b*4+1], g2 = gts[b*4+2], g3 = gts[b*4+3];
    const bool  gt_valid = (g2 > g0) && (g3 > g1);
    const int   cls = labels[b];
    const float area_g = (g2 - g0) * (g3 - g1);

    const int a = __any((lane < 32) ? anyf[b*32 + lane] : 0);

    if (a) {
        unsigned long long k[5];
        #pragma unroll
        for (int j = 0; j < 5; ++j) k[j] = cand[(size_t)b * 320 + j*64 + lane];

        unsigned long long mywin = 0ull;
        for (int r = 0; r < TOPK; ++r) {
            unsigned long long lm = k[0];
            #pragma unroll
            for (int j = 1; j < 5; ++j) lm = k[j] > lm ? k[j] : lm;
            const unsigned long long w = wave_max_u64(lm);
            #pragma unroll
            for (int j = 0; j < 5; ++j) if (k[j] == w) k[j] = 0ull;
            if (lane == r) mywin = w;
        }

        // sel <=> metric >= +0.0 <=> top bit of key set (in-box anchors only).
        if (gt_valid && lane < TOPK && (mywin & 0x8000000000000000ull)) {
            const int i = (int)(~(unsigned int)(mywin & 0xffffffffu));
            const float4 bx = ((const float4*)boxes)[(size_t)b * N + i];
            const float ix1 = fmaxf(bx.x, g0), iy1 = fmaxf(bx.y, g1);
            const float ix2 = fminf(bx.z, g2), iy2 = fminf(bx.w, g3);
            const float inter  = fmaxf(ix2 - ix1, 0.0f) * fmaxf(iy2 - iy1, 0.0f);
            const float area_p = (bx.z - bx.x) * (bx.w - bx.y);
            const float iou = fmaxf(inter / (area_p + area_g - inter), 1e-9f);

            fg[(size_t)b * N + i] = 1.0f;
            ((float4*)tb)[(size_t)b * N + i] = make_float4(g0, g1, g2, g3);
            ts[((size_t)b * N + i) * C + cls] = iou;
        }
    } else {
        // Fallback: single winner = global argmin-d2 anchor (metric always >= 0).
        unsigned long long dk = ~0ull;
        float fiou = 0.0f;
        if (lane < 32) { const FB r = fbr[b*32 + lane]; dk = r.dkey; fiou = r.iou; }
        const unsigned long long m = wave_min_u64(dk);
        if (gt_valid && lane < 32 && dk == m) {
            const int i = (int)(dk & 0xffffffffu);
            fg[(size_t)b * N + i] = 1.0f;
            ((float4*)tb)[(size_t)b * N + i] = make_float4(g0, g1, g2, g3);
            ts[((size_t)b * N + i) * C + cls] = fiou;
        }
    }
}

extern "C" void kernel_launch(void* const* d_in, const int* in_sizes, int n_in,
                              void* d_out, int out_size, void* d_ws, size_t ws_size,
                              hipStream_t stream) {
    const float* scores  = (const float*)d_in[0];
    const float* boxes   = (const float*)d_in[1];
    const float* anchors = (const float*)d_in[2];
    const int*   labels  = (const int*)d_in[3];
    const float* gts     = (const float*)d_in[4];

    const int B = in_sizes[3];
    const int N = in_sizes[2] / 2;
    const int C = in_sizes[0] / (B * N);

    float* tb = (float*)d_out;
    float* ts = tb + (size_t)B * N * 4;
    float* fg = ts + (size_t)B * N * C;

    // Workspace layout (all 16B-aligned).
    unsigned long long* cand = (unsigned long long*)d_ws;          // B*320*8  = 160 KiB
    FB*  fbr  = (FB*)((char*)d_ws + (size_t)B * 320 * 8);          // B*32*16  =  32 KiB
    int* anyf = (int*)((char*)fbr + (size_t)B * 32 * sizeof(FB));  // B*32*4   =   8 KiB

    const size_t n4 = ((size_t)out_size * sizeof(float)) / sizeof(float4);
    zero_fill_kernel<<<2048, 256, 0, stream>>>((float4*)d_out, n4);

    taa_stage1<<<B * G, S1_THREADS, 0, stream>>>(scores, boxes, anchors, labels, gts,
                                                 cand, fbr, anyf, N, C);

    taa_stage2<<<B, 64, 0, stream>>>(boxes, labels, gts, cand, fbr, anyf,
                                     tb, ts, fg, N, C);
}

// Round 5
// 38.389 us; speedup vs baseline: 2.5415x; 1.5440x over previous
//
#include <hip/hip_runtime.h>
#include <math.h>

#define TOPK 10
#define G 8              // stage-1 blocks per batch
#define CHUNK 1050       // N / G
#define NT 256
#define S1_PER 5         // ceil(CHUNK / NT)
#define FILL_BLOCKS 2048

// ---------- helpers ----------

// Order-preserving f32 -> u32 (monotone: a<b  =>  enc(a)<enc(b)).
__device__ __forceinline__ unsigned int f32_ordkey(float f) {
    unsigned int u = __float_as_uint(f);
    return (u & 0x80000000u) ? ~u : (u | 0x80000000u);
}

__device__ __forceinline__ unsigned long long wave_max_u64(unsigned long long k) {
    #pragma unroll
    for (int off = 32; off > 0; off >>= 1) {
        unsigned long long o = __shfl_xor(k, off, 64);
        k = (o > k) ? o : k;
    }
    return k;
}

__device__ __forceinline__ unsigned long long wave_min_u64(unsigned long long k) {
    #pragma unroll
    for (int off = 32; off > 0; off >>= 1) {
        unsigned long long o = __shfl_xor(k, off, 64);
        k = (o < k) ? o : k;
    }
    return k;
}

__device__ __forceinline__ float iou_box(float4 bx, float g0, float g1, float g2,
                                         float g3, float area_g) {
    const float ix1 = fmaxf(bx.x, g0), iy1 = fmaxf(bx.y, g1);
    const float ix2 = fminf(bx.z, g2), iy2 = fminf(bx.w, g3);
    const float inter  = fmaxf(ix2 - ix1, 0.0f) * fmaxf(iy2 - iy1, 0.0f);
    const float area_p = (bx.z - bx.x) * (bx.w - bx.y);
    return fmaxf(inter / (area_p + area_g - inter), 1e-9f);
}

// ---------- fused fill + stage1 ----------
// grid >= FILL_BLOCKS blocks x 256. All blocks: grid-stride float4 zero-fill of
// d_out. Blocks < B*G additionally: stage-1 for (b,g) — anchors always read;
// boxes/scores read ONLY for in-box anchors (~3%). Wave-shuffle reductions only.
__global__ __launch_bounds__(NT) void taa_fused(
    const float* __restrict__ scores,   // B,N,C
    const float* __restrict__ boxes,    // B,N,4
    const float* __restrict__ anchors,  // N,2
    const int*   __restrict__ labels,   // B
    const float* __restrict__ gts,      // B,1,4
    float4* __restrict__ out4, size_t n4,
    unsigned long long* __restrict__ cand,  // [B][G*4*TOPK] = [B][320]
    unsigned long long* __restrict__ dkw,   // [B][G*4]      = [B][32]
    int* __restrict__ anyf,                 // [B][G*4]
    int BG, int N, int C)
{
    const int tid  = threadIdx.x;

    if (blockIdx.x < (unsigned)BG) {
        const int b    = blockIdx.x / G;
        const int g    = blockIdx.x % G;
        const int lane = tid & 63;
        const int wave = tid >> 6;      // 0..3
        const int base = g * CHUNK;

        const float g0 = gts[b*4+0], g1 = gts[b*4+1], g2 = gts[b*4+2], g3 = gts[b*4+3];
        const int   cls = labels[b];
        const float gcx = (g0 + g2) * 0.5f, gcy = (g1 + g3) * 0.5f;
        const float area_g = (g2 - g0) * (g3 - g1);

        unsigned long long key[S1_PER];
        unsigned long long dkey = ~0ull;
        int anyin = 0;

        #pragma unroll
        for (int j = 0; j < S1_PER; ++j) {
            const int ii = tid + j * NT;
            const int i  = base + ii;
            if (ii < CHUNK) {
                const float2 a = ((const float2*)anchors)[i];
                const bool in = (a.x >= g0) && (a.x <= g2) && (a.y >= g1) && (a.y <= g3);
                anyin |= (int)in;

                const float dx = a.x - gcx, dy = a.y - gcy;
                const float d2 = dx*dx + dy*dy;
                const unsigned long long dk =
                    ((unsigned long long)__float_as_uint(d2) << 32) | (unsigned int)i;
                dkey = dk < dkey ? dk : dkey;   // ties -> lower idx (low bits)

                float m = -1.0f;
                if (in) {   // lazy: boxes/scores touched only for in-box anchors
                    const float4 bx = ((const float4*)boxes)[(size_t)b * N + i];
                    const float iou = iou_box(bx, g0, g1, g2, g3, area_g);
                    const float sc = scores[((size_t)b * N + i) * C + cls];
                    const float cs = 1.0f / (1.0f + expf(-sc));
                    const float i2 = iou * iou;
                    m = sqrtf(cs) * (i2 * i2 * i2);
                }
                key[j] = ((unsigned long long)f32_ordkey(m) << 32) | (unsigned int)(~(unsigned int)i);
            } else {
                key[j] = 0ull;          // below any real key (key(-1.0) > 0)
            }
        }

        // Wave top-10 by iterative max + zero-out (keys unique: idx in low bits).
        unsigned long long* wc = cand + ((size_t)b * (G*4*TOPK)) + (g*4 + wave) * TOPK;
        for (int r = 0; r < TOPK; ++r) {
            unsigned long long lm = key[0];
            #pragma unroll
            for (int j = 1; j < S1_PER; ++j) lm = key[j] > lm ? key[j] : lm;
            const unsigned long long w = wave_max_u64(lm);
            #pragma unroll
            for (int j = 0; j < S1_PER; ++j) if (key[j] == w) key[j] = 0ull;
            if (lane == 0) wc[r] = w;
        }

        // Wave any(is_in) + min-d2 key.
        const int wany = __any(anyin);
        const unsigned long long wdk = wave_min_u64(dkey);
        if (lane == 0) {
            anyf[b * (G*4) + g*4 + wave] = wany;
            dkw [b * (G*4) + g*4 + wave] = wdk;
        }
    }

    // Zero-fill slice (all blocks).
    const size_t stride = (size_t)gridDim.x * NT;
    const float4 z = make_float4(0.f, 0.f, 0.f, 0.f);
    for (size_t i = (size_t)blockIdx.x * NT + tid; i < n4; i += stride)
        out4[i] = z;
}

// ---------- stage 2: merge + scatter ----------
// grid = B blocks x 64 threads.
__global__ __launch_bounds__(64) void taa_stage2(
    const float* __restrict__ boxes,    // B,N,4
    const int*   __restrict__ labels,   // B
    const float* __restrict__ gts,      // B,1,4
    const unsigned long long* __restrict__ cand,
    const unsigned long long* __restrict__ dkw,
    const int* __restrict__ anyf,
    float* __restrict__ tb, float* __restrict__ ts, float* __restrict__ fg,
    int N, int C)
{
    const int b    = blockIdx.x;
    const int lane = threadIdx.x;

    const float g0 = gts[b*4+0], g1 = gts[b*4+1], g2 = gts[b*4+2], g3 = gts[b*4+3];
    const bool  gt_valid = (g2 > g0) && (g3 > g1);
    const int   cls = labels[b];
    const float area_g = (g2 - g0) * (g3 - g1);

    const int a = __any((lane < 32) ? anyf[b*32 + lane] : 0);

    int   wi  = -1;       // winner anchor index for this lane (if any)
    if (a) {
        unsigned long long k[5];
        #pragma unroll
        for (int j = 0; j < 5; ++j) k[j] = cand[(size_t)b * 320 + j*64 + lane];

        unsigned long long mywin = 0ull;
        for (int r = 0; r < TOPK; ++r) {
            unsigned long long lm = k[0];
            #pragma unroll
            for (int j = 1; j < 5; ++j) lm = k[j] > lm ? k[j] : lm;
            const unsigned long long w = wave_max_u64(lm);
            #pragma unroll
            for (int j = 0; j < 5; ++j) if (k[j] == w) k[j] = 0ull;
            if (lane == r) mywin = w;
        }
        // sel <=> metric >= +0.0 <=> top bit set (only in-box anchors qualify).
        if (lane < TOPK && (mywin & 0x8000000000000000ull))
            wi = (int)(~(unsigned int)(mywin & 0xffffffffu));
    } else {
        // Fallback: single winner = global argmin-d2 (metric > 0 always).
        unsigned long long dk = (lane < 32) ? dkw[b*32 + lane] : ~0ull;
        const unsigned long long m = wave_min_u64(dk);
        if (lane == 0) wi = (int)(m & 0xffffffffu);
    }

    if (gt_valid && wi >= 0) {
        const float4 bx = ((const float4*)boxes)[(size_t)b * N + wi];
        const float iou = iou_box(bx, g0, g1, g2, g3, area_g);
        fg[(size_t)b * N + wi] = 1.0f;
        ((float4*)tb)[(size_t)b * N + wi] = make_float4(g0, g1, g2, g3);
        ts[((size_t)b * N + wi) * C + cls] = iou;
    }
}

extern "C" void kernel_launch(void* const* d_in, const int* in_sizes, int n_in,
                              void* d_out, int out_size, void* d_ws, size_t ws_size,
                              hipStream_t stream) {
    const float* scores  = (const float*)d_in[0];
    const float* boxes   = (const float*)d_in[1];
    const float* anchors = (const float*)d_in[2];
    const int*   labels  = (const int*)d_in[3];
    const float* gts     = (const float*)d_in[4];

    const int B = in_sizes[3];
    const int N = in_sizes[2] / 2;
    const int C = in_sizes[0] / (B * N);
    const int BG = B * G;

    float* tb = (float*)d_out;
    float* ts = tb + (size_t)B * N * 4;
    float* fg = ts + (size_t)B * N * C;

    // Workspace layout (8B-aligned).
    unsigned long long* cand = (unsigned long long*)d_ws;                 // B*320*8
    unsigned long long* dkw  = cand + (size_t)B * 320;                    // B*32*8
    int*                anyf = (int*)(dkw + (size_t)B * 32);              // B*32*4

    const size_t n4 = ((size_t)out_size * sizeof(float)) / sizeof(float4);
    const int grid = (FILL_BLOCKS > BG) ? FILL_BLOCKS : BG;

    taa_fused<<<grid, NT, 0, stream>>>(scores, boxes, anchors, labels, gts,
                                       (float4*)d_out, n4, cand, dkw, anyf,
                                       BG, N, C);

    taa_stage2<<<B, 64, 0, stream>>>(boxes, labels, gts, cand, dkw, anyf,
                                     tb, ts, fg, N, C);
}